// Round 7
// baseline (478.854 us; speedup 1.0000x reference)
//
#include <hip/hip_runtime.h>
#include <math.h>

#define VOCABN 100
#define EMBEDN 50
#define HID 30
#define NB 512
#define NT 512
#define G4 120  // 4*HID

typedef float v2f __attribute__((ext_vector_type(2)));

__device__ __forceinline__ float tanh_f(float x) { return 1.0f - 2.0f / (1.0f + __expf(2.0f * x)); }
__device__ __forceinline__ v2f mk2(float a, float b) { v2f r; r[0] = a; r[1] = b; return r; }

// v_permlane32_swap(x,x): r[0] = lo-half broadcast to all lanes, r[1] = hi-half.
// VALU pipe (~8cyc) vs ds_permute (~120cyc).
__device__ __forceinline__ void bcast_halves(float x, float& lo_all, float& hi_all) {
  auto r = __builtin_amdgcn_permlane32_swap(__builtin_bit_cast(unsigned, x),
                                            __builtin_bit_cast(unsigned, x), false, false);
  lo_all = __builtin_bit_cast(float, (unsigned)r[0]);
  hi_all = __builtin_bit_cast(float, (unsigned)r[1]);
}

__device__ __forceinline__ float rdlane(float v, int k) {
  return __builtin_bit_cast(float, __builtin_amdgcn_readlane(__builtin_bit_cast(int, v), k));
}

// ---------------- prep: xpe[tok][g] = emb[tok]@w_ih1^T + b_ih1 + b_hh1 ; b2s = b_ih2+b_hh2
// also outc[v] = lb2[v] + relu(lb1) . lw2[v]  (output row for masked timesteps)
__global__ void prep_kernel(const float* __restrict__ emb,
                            const float* __restrict__ w_ih1,
                            const float* __restrict__ b_ih1,
                            const float* __restrict__ b_hh1,
                            const float* __restrict__ b_ih2,
                            const float* __restrict__ b_hh2,
                            const float* __restrict__ lw2,
                            const float* __restrict__ lb1,
                            const float* __restrict__ lb2,
                            float* __restrict__ xpe, float* __restrict__ b2s,
                            float* __restrict__ outc) {
  __shared__ float e[EMBEDN];
  int r = blockIdx.x;
  int tid = threadIdx.x;
  if (tid < EMBEDN) e[tid] = emb[r * EMBEDN + tid];
  __syncthreads();
  if (tid < G4) {
    float s = b_ih1[tid] + b_hh1[tid];
#pragma unroll
    for (int k = 0; k < EMBEDN; ++k) s = fmaf(e[k], w_ih1[tid * EMBEDN + k], s);
    xpe[r * G4 + tid] = s;
    if (r == 0) b2s[tid] = b_ih2[tid] + b_hh2[tid];
  }
  if (r == 0 && tid < VOCABN) {
    float o = lb2[tid];
#pragma unroll
    for (int k = 0; k < HID; ++k) o = fmaf(fmaxf(lb1[k], 0.f), lw2[tid * HID + k], o);
    outc[tid] = o;
  }
}

// ---------------- scan: ONE WAVE per sequence. No barriers. h1 broadcast via
// v_readlane -> SGPRs (free broadcast as scalar FMA operand). h2 feedback via a
// 32-float LDS slot, read early (only needed for the w_hh2 dot, which has a full
// step of slack). w_hh1/w_ih2 rows register-resident (120 VGPR); w_hh2 streams
// from LDS (conflict-free 2-way v2f reads) to stay under the allocator's cap.
__global__ void __launch_bounds__(64, 1) scan_kernel(
    const int* __restrict__ batch_x, const int* __restrict__ lens,
    const float* __restrict__ xpe, const float* __restrict__ b2s,
    const float* __restrict__ w_hh1, const float* __restrict__ w_ih2,
    const float* __restrict__ w_hh2, float* __restrict__ h2g) {
  __shared__ __align__(16) float wh_lds[G4 * HID];  // w_hh2 [120][30], 14.4 KB
  __shared__ int tok_lds[NT];                       // 2 KB
  __shared__ __align__(8) float h2_lds[32];

  const int b = blockIdx.x;
  const int lane = threadIdx.x;
  const int half = lane >> 5;
  const int j = lane & 31;
  const int jj = (j < HID) ? j : (HID - 1);
  // half0 lane j: gates (i_j, f_j); half1 lane j: gates (g_j, o_j)
  const int gA = half ? (jj + 2 * HID) : jj;
  const int gB = half ? (jj + 3 * HID) : (jj + HID);
  const float bg = half ? 2.0f : 1.0f;  // beta: 1 -> sigmoid, 2 -> tanh

  // one-time staging (single wave: in-wave ordering, no barriers)
  for (int i = lane; i < G4 * HID; i += 64) wh_lds[i] = w_hh2[i];
  const int* xrow = batch_x + b * NT;
#pragma unroll
  for (int i = 0; i < NT / 64; ++i) tok_lds[lane + (i << 6)] = xrow[lane + (i << 6)];
  if (lane < 32) h2_lds[lane] = 0.f;

  // register-resident weight rows: w_hh1 and w_ih2, gates gA and gB
  float w1A[HID], w1B[HID], wiA[HID], wiB[HID];
#pragma unroll
  for (int k = 0; k < HID; ++k) {
    w1A[k] = w_hh1[gA * HID + k];
    w1B[k] = w_hh1[gB * HID + k];
    wiA[k] = w_ih2[gA * HID + k];
    wiB[k] = w_ih2[gB * HID + k];
  }
  const float b2A = b2s[gA], b2B = b2s[gB];
  const int len = lens[b];

  // h1 state lives in SGPRs (uniform values)
  float hs1[HID];
#pragma unroll
  for (int k = 0; k < HID; ++k) hs1[k] = 0.0f;
  float c1 = 0.f, c2 = 0.f;

  // xpe 2-deep prefetch pipeline
  int t0 = tok_lds[0];
  float xaC = xpe[t0 * G4 + gA];
  float xbC = xpe[t0 * G4 + gB];
  int t1 = tok_lds[1];
  float xaN = xpe[t1 * G4 + gA];
  float xbN = xpe[t1 * G4 + gB];

  for (int t = 0; t < len; ++t) {
    // ---- early LDS issues: h2[t-1] (broadcast, free) + w_hh2 rows (2-way, free)
    v2f h2p[15], whAv[15], whBv[15];
    const v2f* h2v = (const v2f*)h2_lds;
    const v2f* whA_ = (const v2f*)&wh_lds[gA * HID];
    const v2f* whB_ = (const v2f*)&wh_lds[gB * HID];
#pragma unroll
    for (int p = 0; p < 15; ++p) {
      h2p[p] = h2v[p];
      whAv[p] = whA_[p];
      whBv[p] = whB_[p];
    }
    int tp = t + 2;
    int tk2 = tok_lds[(tp < NT) ? tp : (NT - 1)];

    // ---- w_hh2 . h2[t-1]  (off the critical chain: inputs known since last step)
    v2f rA = mk2(0.f, 0.f), rB = mk2(0.f, 0.f);
#pragma unroll
    for (int p = 0; p < 15; ++p) {
      rA = __builtin_elementwise_fma(h2p[p], whAv[p], rA);
      rB = __builtin_elementwise_fma(h2p[p], whBv[p], rB);
    }

    // ---- layer1: w_hh1 . h1[t-1] (SGPR broadcast), split accumulator chains
    float a0a = 0.f, a0b = 0.f, a1a = 0.f, a1b = 0.f;
#pragma unroll
    for (int k = 0; k < 15; ++k) {
      a0a = fmaf(hs1[k], w1A[k], a0a);
      a1a = fmaf(hs1[k], w1B[k], a1a);
      a0b = fmaf(hs1[k + 15], w1A[k + 15], a0b);
      a1b = fmaf(hs1[k + 15], w1B[k + 15], a1b);
    }
    float a0 = a0a + a0b + xaC;
    float a1 = a1a + a1b + xbC;
    float sA = 1.0f - bg / (1.0f + __expf(bg * a0));
    float sB = 1.0f - 1.0f / (1.0f + __expf(a1));
    float i1, g1, f1, o1;
    bcast_halves(sA, i1, g1);
    bcast_halves(sB, f1, o1);
    c1 = fmaf(f1, c1, i1 * g1);
    float h1n = o1 * tanh_f(c1);  // h1[t], channel j in every lane group

    // ---- h1[t] -> SGPRs via readlane (lanes 0..29 hold channels 0..29)
#pragma unroll
    for (int k = 0; k < HID; ++k) hs1[k] = rdlane(h1n, k);

    // ---- layer2: w_ih2 . h1[t] (SGPR broadcast) + rA/rB + bias
    float q0a = 0.f, q0b = 0.f, q1a = 0.f, q1b = 0.f;
#pragma unroll
    for (int k = 0; k < 15; ++k) {
      q0a = fmaf(hs1[k], wiA[k], q0a);
      q1a = fmaf(hs1[k], wiB[k], q1a);
      q0b = fmaf(hs1[k + 15], wiA[k + 15], q0b);
      q1b = fmaf(hs1[k + 15], wiB[k + 15], q1b);
    }
    float q0 = q0a + q0b + rA[0] + rA[1] + b2A;
    float q1 = q1a + q1b + rB[0] + rB[1] + b2B;
    float uA = 1.0f - bg / (1.0f + __expf(bg * q0));
    float uB = 1.0f - 1.0f / (1.0f + __expf(q1));
    float i2, g2, f2, o2;
    bcast_halves(uA, i2, g2);
    bcast_halves(uB, f2, o2);
    c2 = fmaf(f2, c2, i2 * g2);
    float h2n = o2 * tanh_f(c2);  // h2[t]

    // ---- commit state + async store
    if (lane < 32) h2_lds[j] = h2n;
    if (lane < HID) h2g[((size_t)t * NB + b) * HID + lane] = h2n;

    // rotate xpe pipeline (2-step slack; global loads never waited on in-chain)
    xaC = xaN;
    xbC = xbN;
    xaN = xpe[tk2 * G4 + gA];
    xbN = xpe[tk2 * G4 + gB];
  }
}

// ---------------- head MLP: wave-autonomous, no in-loop barriers.
// wave handles 64 consecutive rows; masked rows -> store precomputed outc.
__global__ void __launch_bounds__(256) final_kernel(
    const float* __restrict__ h2g, const int* __restrict__ lens,
    const float* __restrict__ lw1, const float* __restrict__ lb1,
    const float* __restrict__ lw2, const float* __restrict__ lb2,
    const float* __restrict__ outc, float* __restrict__ out) {
  __shared__ float2 w1p[15][32];   // w1p[p][j] = lw1[j][2p..2p+1]
  __shared__ float2 w2p[15][112];  // w2p[p][v] = lw2[v][2p..2p+1]
  __shared__ float hmb[4][32];     // per-wave hmid broadcast
  const int tid = threadIdx.x;
  for (int i = tid; i < 15 * HID; i += 256) {
    int p = i % 15, jj_ = i / 15;
    float2 w; w.x = lw1[jj_ * HID + 2 * p]; w.y = lw1[jj_ * HID + 2 * p + 1];
    w1p[p][jj_] = w;
  }
  for (int i = tid; i < 15 * VOCABN; i += 256) {
    int p = i % 15, v = i / 15;
    float2 w; w.x = lw2[v * HID + 2 * p]; w.y = lw2[v * HID + 2 * p + 1];
    w2p[p][v] = w;
  }
  __syncthreads();
  const int wid = tid >> 6, lane = tid & 63;
  const int jj = (lane < HID) ? lane : (HID - 1);
  const int l1 = (lane < 50) ? lane : 49;  // this lane's vocab cols: l1, l1+50
  const float lb1v = lb1[jj];
  const float lb2a = lb2[l1], lb2b = lb2[l1 + 50];
  const float oca = outc[l1], ocb = outc[l1 + 50];
  const int wgid = blockIdx.x * 4 + wid;
  const int r0 = wgid * 64;
  const float2* qb = (const float2*)hmb[wid];
  for (int r = r0; r < r0 + 64; ++r) {
    int b = r >> 9, t = r & (NT - 1);
    int len = lens[b];
    float* orow = out + (size_t)r * VOCABN;
    if (t >= len) {
      if (lane < 50) { orow[l1] = oca; orow[l1 + 50] = ocb; }
      continue;
    }
    const float2* hp = (const float2*)(h2g + (size_t)(t * NB + b) * HID);
    float2 h[15];
#pragma unroll
    for (int p = 0; p < 15; ++p) h[p] = hp[p];
    float m = lb1v;
#pragma unroll
    for (int p = 0; p < 15; ++p) {
      float2 w = w1p[p][jj];
      m = fmaf(h[p].x, w.x, m);
      m = fmaf(h[p].y, w.y, m);
    }
    m = fmaxf(m, 0.f);
    if (lane < HID) hmb[wid][lane] = m;
    // same-wave LDS write->read: in-order DS pipe, no barrier needed
    float2 q[15];
#pragma unroll
    for (int p = 0; p < 15; ++p) q[p] = qb[p];
    float oa = lb2a, ob = lb2b;
#pragma unroll
    for (int p = 0; p < 15; ++p) {
      float2 wa = w2p[p][l1];
      float2 wb = w2p[p][l1 + 50];
      oa = fmaf(q[p].x, wa.x, oa);
      oa = fmaf(q[p].y, wa.y, oa);
      ob = fmaf(q[p].x, wb.x, ob);
      ob = fmaf(q[p].y, wb.y, ob);
    }
    if (lane < 50) { orow[l1] = oa; orow[l1 + 50] = ob; }
  }
}

extern "C" void kernel_launch(void* const* d_in, const int* in_sizes, int n_in,
                              void* d_out, int out_size, void* d_ws, size_t ws_size,
                              hipStream_t stream) {
  const int* batch_x = (const int*)d_in[0];
  const int* lens = (const int*)d_in[1];
  const float* emb = (const float*)d_in[2];
  const float* w_ih1 = (const float*)d_in[3];
  const float* w_hh1 = (const float*)d_in[4];
  const float* b_ih1 = (const float*)d_in[5];
  const float* b_hh1 = (const float*)d_in[6];
  const float* w_ih2 = (const float*)d_in[7];
  const float* w_hh2 = (const float*)d_in[8];
  const float* b_ih2 = (const float*)d_in[9];
  const float* b_hh2 = (const float*)d_in[10];
  const float* lw1 = (const float*)d_in[11];
  const float* lb1 = (const float*)d_in[12];
  const float* lw2 = (const float*)d_in[13];
  const float* lb2 = (const float*)d_in[14];
  float* out = (float*)d_out;

  char* ws = (char*)d_ws;
  float* xpe = (float*)ws;                 // 100*120 floats
  float* b2s = (float*)(ws + 48 * 1024);   // 120 floats
  float* outc = (float*)(ws + 56 * 1024);  // 100 floats
  float* h2g = (float*)(ws + 64 * 1024);   // 512*512*30 floats (~31.5 MB)

  prep_kernel<<<VOCABN, 128, 0, stream>>>(emb, w_ih1, b_ih1, b_hh1, b_ih2, b_hh2,
                                          lw2, lb1, lb2, xpe, b2s, outc);
  scan_kernel<<<NB, 64, 0, stream>>>(batch_x, lens, xpe, b2s, w_hh1, w_ih2, w_hh2, h2g);
  final_kernel<<<(NB * NT) / 256, 256, 0, stream>>>(h2g, lens, lw1, lb1, lw2, lb2, outc, out);
}

// Round 8
// 367.518 us; speedup vs baseline: 1.3029x; 1.3029x over previous
//
#include <hip/hip_runtime.h>
#include <math.h>

#define VOCABN 100
#define EMBEDN 50
#define HID 30
#define NB 512
#define NT 512
#define G4 120  // 4*HID

__device__ __forceinline__ float fastrcp(float x) {
  float r;
  asm("v_rcp_f32 %0, %1" : "=v"(r) : "v"(x));
  return r;
}
__device__ __forceinline__ float tanh_fast(float x) {
  return 1.0f - 2.0f * fastrcp(1.0f + __expf(2.0f * x));
}
// v_permlane32_swap(x,x): lo_all = lanes[0..31]'s value broadcast into all lanes' slot,
// hi_all = lanes[32..63]'s value. VALU pipe (~8cyc) vs ds_permute (~120cyc).
__device__ __forceinline__ void bcast_halves(float x, float& lo_all, float& hi_all) {
  auto r = __builtin_amdgcn_permlane32_swap(__builtin_bit_cast(unsigned, x),
                                            __builtin_bit_cast(unsigned, x), false, false);
  lo_all = __builtin_bit_cast(float, (unsigned)r[0]);
  hi_all = __builtin_bit_cast(float, (unsigned)r[1]);
}
__device__ __forceinline__ float rdlane(float v, int k) {
  return __builtin_bit_cast(float, __builtin_amdgcn_readlane(__builtin_bit_cast(int, v), k));
}
// Raw workgroup barrier: LDS-visibility only (lgkmcnt), no vmcnt drain.
__device__ __forceinline__ void tick_barrier() {
  asm volatile("s_waitcnt lgkmcnt(0)" ::: "memory");
  __builtin_amdgcn_s_barrier();
  asm volatile("" ::: "memory");
}

// ---------------- prep: xpe[tok][g] = emb[tok]@w_ih1^T + b_ih1 + b_hh1 ; b2s = b_ih2+b_hh2
// also outc[v] = lb2[v] + relu(lb1) . lw2[v]  (output row for masked timesteps)
__global__ void prep_kernel(const float* __restrict__ emb,
                            const float* __restrict__ w_ih1,
                            const float* __restrict__ b_ih1,
                            const float* __restrict__ b_hh1,
                            const float* __restrict__ b_ih2,
                            const float* __restrict__ b_hh2,
                            const float* __restrict__ lw2,
                            const float* __restrict__ lb1,
                            const float* __restrict__ lb2,
                            float* __restrict__ xpe, float* __restrict__ b2s,
                            float* __restrict__ outc) {
  __shared__ float e[EMBEDN];
  int r = blockIdx.x;
  int tid = threadIdx.x;
  if (tid < EMBEDN) e[tid] = emb[r * EMBEDN + tid];
  __syncthreads();
  if (tid < G4) {
    float s = b_ih1[tid] + b_hh1[tid];
#pragma unroll
    for (int k = 0; k < EMBEDN; ++k) s = fmaf(e[k], w_ih1[tid * EMBEDN + k], s);
    xpe[r * G4 + tid] = s;
    if (r == 0) b2s[tid] = b_ih2[tid] + b_hh2[tid];
  }
  if (r == 0 && tid < VOCABN) {
    float o = lb2[tid];
#pragma unroll
    for (int k = 0; k < HID; ++k) o = fmaf(fmaxf(lb1[k], 0.f), lw2[tid * HID + k], o);
    outc[tid] = o;
  }
}

// ---------------- scan: 3 pipelined waves per sequence; recurrent state in SGPRs.
// W0(t=k): layer1 rec, h1 self-feedback via readlane->SGPR; writes h1buf for W1.
// W1(t=k-1): u = w_ih2 . h1 (reads h1buf, 1-tick slack); writes ubuf.
// W2(t=k-2): layer2 rec (h2 self-feedback via readlane->SGPR) + u + store.
// No LDS read is on the critical chain; barrier is lgkm-only.
__global__ void __launch_bounds__(192) scan_kernel(
    const int* __restrict__ batch_x, const int* __restrict__ lens,
    const float* __restrict__ xpe, const float* __restrict__ b2s,
    const float* __restrict__ w_hh1, const float* __restrict__ w_ih2,
    const float* __restrict__ w_hh2, float* __restrict__ h2g) {
  __shared__ __align__(16) float h1buf[2][32];
  __shared__ __align__(16) float2 ubuf[2][64];
  __shared__ int tok_lds[NT];

  const int b = blockIdx.x;
  const int tid = threadIdx.x;
  const int wid = tid >> 6;  // 0,1,2
  const int lane = tid & 63;
  const int half = lane >> 5;
  const int j = lane & 31;
  const int jj = (j < HID) ? j : (HID - 1);
  // half0 lane j: gates (i_j, f_j); half1 lane j: gates (g_j, o_j)
  const int gA = half ? (jj + 2 * HID) : jj;
  const int gB = half ? (jj + 3 * HID) : (jj + HID);
  const float bg = half ? 2.0f : 1.0f;  // beta: 1 -> sigmoid, 2 -> tanh

  const int* xrow = batch_x + b * NT;
  for (int i = tid; i < NT; i += 192) tok_lds[i] = xrow[i];

  // per-wave weight slice: rows gA,gB of this wave's matrix (60 VGPR)
  const float* wsrc = (wid == 0) ? w_hh1 : (wid == 1) ? w_ih2 : w_hh2;
  float wA[HID], wB[HID];
#pragma unroll
  for (int k = 0; k < HID; ++k) {
    wA[k] = wsrc[gA * HID + k];
    wB[k] = wsrc[gB * HID + k];
  }
  const float b2A = b2s[gA], b2B = b2s[gB];
  const int len = lens[b];
  float c = 0.f;     // c1 (W0) / c2 (W2)
  float hs[HID];     // uniform (SGPR) recurrent state: h1 (W0) / h2 (W2)
#pragma unroll
  for (int k = 0; k < HID; ++k) hs[k] = 0.f;
  float xaC = 0.f, xbC = 0.f, xaN = 0.f, xbN = 0.f;
  __syncthreads();  // tokens staged
  if (wid == 0) {
    int t0 = tok_lds[0];
    xaC = xpe[t0 * G4 + gA];
    xbC = xpe[t0 * G4 + gB];
    int t1 = tok_lds[1];
    xaN = xpe[t1 * G4 + gA];
    xbN = xpe[t1 * G4 + gB];
  }

  for (int k = 0; k < len + 2; ++k) {
    if (wid == 0) {
      if (k < len) {
        // layer1: w_hh1 . h1[k-1]  (SGPR broadcast, 4 interleaved chains)
        float a0a = 0.f, a0b = 0.f, a1a = 0.f, a1b = 0.f;
#pragma unroll
        for (int p = 0; p < 15; ++p) {
          a0a = fmaf(hs[p], wA[p], a0a);
          a1a = fmaf(hs[p], wB[p], a1a);
          a0b = fmaf(hs[p + 15], wA[p + 15], a0b);
          a1b = fmaf(hs[p + 15], wB[p + 15], a1b);
        }
        float a0 = a0a + a0b + xaC;
        float a1 = a1a + a1b + xbC;
        float sA = 1.0f - bg * fastrcp(1.0f + __expf(bg * a0));
        float sB = 1.0f - fastrcp(1.0f + __expf(a1));
        float i1, g1, f1, o1;
        bcast_halves(sA, i1, g1);
        bcast_halves(sB, f1, o1);
        c = fmaf(f1, c, i1 * g1);
        float h1n = o1 * tanh_fast(c);  // h1[k], channel jj
#pragma unroll
        for (int p = 0; p < HID; ++p) hs[p] = rdlane(h1n, p);
        if (lane < 32) h1buf[k & 1][j] = h1n;
        // rotate 2-deep xpe prefetch (global loads fly across the raw barrier)
        xaC = xaN;
        xbC = xbN;
        int t2 = (k + 2 < len) ? tok_lds[k + 2] : 0;
        xaN = xpe[t2 * G4 + gA];
        xbN = xpe[t2 * G4 + gB];
      }
    } else if (wid == 1) {
      int myT = k - 1;
      if (myT >= 0 && myT < len) {
        const float2* h1p = (const float2*)h1buf[(k - 1) & 1];  // uniform broadcast reads
        float q0a = 0.f, q0b = 0.f, q1a = 0.f, q1b = 0.f;
#pragma unroll
        for (int p = 0; p < 15; ++p) {
          float2 hp = h1p[p];
          if (p < 8) {
            q0a = fmaf(hp.x, wA[2 * p], q0a);
            q1a = fmaf(hp.x, wB[2 * p], q1a);
            q0a = fmaf(hp.y, wA[2 * p + 1], q0a);
            q1a = fmaf(hp.y, wB[2 * p + 1], q1a);
          } else {
            q0b = fmaf(hp.x, wA[2 * p], q0b);
            q1b = fmaf(hp.x, wB[2 * p], q1b);
            q0b = fmaf(hp.y, wA[2 * p + 1], q0b);
            q1b = fmaf(hp.y, wB[2 * p + 1], q1b);
          }
        }
        float2 u;
        u.x = q0a + q0b;
        u.y = q1a + q1b;
        ubuf[(k - 1) & 1][lane] = u;  // u[myT] -> slot myT&1
      }
    } else {
      int myT = k - 2;
      if (myT >= 0 && myT < len) {
        float2 u = ubuf[k & 1][lane];  // u[myT], slot (k-2)&1 == k&1 (1-tick slack)
        float q0a = 0.f, q0b = 0.f, q1a = 0.f, q1b = 0.f;
#pragma unroll
        for (int p = 0; p < 15; ++p) {
          q0a = fmaf(hs[p], wA[p], q0a);
          q1a = fmaf(hs[p], wB[p], q1a);
          q0b = fmaf(hs[p + 15], wA[p + 15], q0b);
          q1b = fmaf(hs[p + 15], wB[p + 15], q1b);
        }
        float q0 = q0a + q0b + u.x + b2A;
        float q1 = q1a + q1b + u.y + b2B;
        float uA = 1.0f - bg * fastrcp(1.0f + __expf(bg * q0));
        float uB = 1.0f - fastrcp(1.0f + __expf(q1));
        float i2, g2, f2, o2;
        bcast_halves(uA, i2, g2);
        bcast_halves(uB, f2, o2);
        c = fmaf(f2, c, i2 * g2);
        float h2n = o2 * tanh_fast(c);  // h2[myT]
#pragma unroll
        for (int p = 0; p < HID; ++p) hs[p] = rdlane(h2n, p);
        if (lane < HID) h2g[((size_t)myT * NB + b) * HID + lane] = h2n;  // async store
      }
    }
    tick_barrier();
  }
}

// ---------------- head MLP: no LDS at all. Per-lane hoisted weights; hmid broadcast
// via readlane->SGPR; next-row global prefetch; 2-row ping-pong.
// wave -> 64 consecutive rows of one batch b (64 | 512, so b is constant per wave).
__global__ void __launch_bounds__(256)
__attribute__((amdgpu_waves_per_eu(1, 2)))
final_kernel(const float* __restrict__ h2g, const int* __restrict__ lens,
             const float* __restrict__ lw1, const float* __restrict__ lb1,
             const float* __restrict__ lw2, const float* __restrict__ lb2,
             const float* __restrict__ outc, float* __restrict__ out) {
  const int tid = threadIdx.x;
  const int wid = tid >> 6, lane = tid & 63;
  const int jj = (lane < HID) ? lane : (HID - 1);
  const int l1 = (lane < 50) ? lane : 49;  // this lane's vocab cols: l1, l1+50

  // hoisted per-lane weights (global, loop-invariant)
  float w1x[15], w1y[15];  // lw1 row jj, pairs
#pragma unroll
  for (int p = 0; p < 15; ++p) {
    w1x[p] = lw1[jj * HID + 2 * p];
    w1y[p] = lw1[jj * HID + 2 * p + 1];
  }
  float w2a[HID], w2b[HID];  // lw2 rows l1, l1+50
#pragma unroll
  for (int k = 0; k < HID; ++k) {
    w2a[k] = lw2[l1 * HID + k];
    w2b[k] = lw2[(l1 + 50) * HID + k];
  }
  const float lb1v = lb1[jj];
  const float lb2a = lb2[l1], lb2b = lb2[l1 + 50];
  const float oca = outc[l1], ocb = outc[l1 + 50];

  const int wgid = blockIdx.x * 4 + wid;
  const int r0 = wgid * 64;
  const int bb = r0 >> 9;  // constant for the whole wave
  const int t0 = r0 & (NT - 1);
  const int len = lens[bb];

#define LOAD_ROW(dst, tt_)                                                     \
  {                                                                            \
    const float2* hp = (const float2*)(h2g + ((size_t)((tt_)*NB + bb)) * HID); \
    _Pragma("unroll") for (int p = 0; p < 15; ++p) dst[p] = hp[p];             \
  }

#define PROC_ROW(hb, tt_)                                                   \
  {                                                                         \
    float* orow = out + ((size_t)(bb * NT + (tt_))) * VOCABN;               \
    if ((tt_) >= len) {                                                     \
      if (lane < 50) {                                                      \
        orow[l1] = oca;                                                     \
        orow[l1 + 50] = ocb;                                                \
      }                                                                     \
    } else {                                                                \
      float ma = lb1v, mb = 0.f;                                            \
      _Pragma("unroll") for (int p = 0; p < 15; ++p) {                      \
        if (p < 8) {                                                        \
          ma = fmaf(hb[p].x, w1x[p], ma);                                   \
          ma = fmaf(hb[p].y, w1y[p], ma);                                   \
        } else {                                                            \
          mb = fmaf(hb[p].x, w1x[p], mb);                                   \
          mb = fmaf(hb[p].y, w1y[p], mb);                                   \
        }                                                                   \
      }                                                                     \
      float m = fmaxf(ma + mb, 0.f);                                        \
      float sm[HID];                                                        \
      _Pragma("unroll") for (int k = 0; k < HID; ++k) sm[k] = rdlane(m, k); \
      float oa0 = lb2a, oa1 = 0.f, ob0 = lb2b, ob1 = 0.f;                   \
      _Pragma("unroll") for (int k = 0; k < 15; ++k) {                      \
        oa0 = fmaf(sm[k], w2a[k], oa0);                                     \
        ob0 = fmaf(sm[k], w2b[k], ob0);                                     \
        oa1 = fmaf(sm[k + 15], w2a[k + 15], oa1);                           \
        ob1 = fmaf(sm[k + 15], w2b[k + 15], ob1);                           \
      }                                                                     \
      if (lane < 50) {                                                      \
        orow[l1] = oa0 + oa1;                                               \
        orow[l1 + 50] = ob0 + ob1;                                          \
      }                                                                     \
    }                                                                       \
  }

  float2 hA[15], hB[15];
  LOAD_ROW(hA, t0)
  for (int t = t0; t < t0 + 64; t += 2) {
    int tn1 = t + 1;
    LOAD_ROW(hB, tn1)       // prefetch row t+1 while processing t
    PROC_ROW(hA, t)
    int tn2 = (t + 2 < NT) ? (t + 2) : (NT - 1);
    LOAD_ROW(hA, tn2)       // prefetch row t+2 while processing t+1
    PROC_ROW(hB, tn1)
  }
#undef LOAD_ROW
#undef PROC_ROW
}

extern "C" void kernel_launch(void* const* d_in, const int* in_sizes, int n_in,
                              void* d_out, int out_size, void* d_ws, size_t ws_size,
                              hipStream_t stream) {
  const int* batch_x = (const int*)d_in[0];
  const int* lens = (const int*)d_in[1];
  const float* emb = (const float*)d_in[2];
  const float* w_ih1 = (const float*)d_in[3];
  const float* w_hh1 = (const float*)d_in[4];
  const float* b_ih1 = (const float*)d_in[5];
  const float* b_hh1 = (const float*)d_in[6];
  const float* w_ih2 = (const float*)d_in[7];
  const float* w_hh2 = (const float*)d_in[8];
  const float* b_ih2 = (const float*)d_in[9];
  const float* b_hh2 = (const float*)d_in[10];
  const float* lw1 = (const float*)d_in[11];
  const float* lb1 = (const float*)d_in[12];
  const float* lw2 = (const float*)d_in[13];
  const float* lb2 = (const float*)d_in[14];
  float* out = (float*)d_out;

  char* ws = (char*)d_ws;
  float* xpe = (float*)ws;                 // 100*120 floats
  float* b2s = (float*)(ws + 48 * 1024);   // 120 floats
  float* outc = (float*)(ws + 56 * 1024);  // 100 floats
  float* h2g = (float*)(ws + 64 * 1024);   // 512*512*30 floats (~31.5 MB)

  prep_kernel<<<VOCABN, 128, 0, stream>>>(emb, w_ih1, b_ih1, b_hh1, b_ih2, b_hh2,
                                          lw2, lb1, lb2, xpe, b2s, outc);
  scan_kernel<<<NB, 192, 0, stream>>>(batch_x, lens, xpe, b2s, w_hh1, w_ih2, w_hh2, h2g);
  final_kernel<<<(NB * NT) / 256, 256, 0, stream>>>(h2g, lens, lw1, lb1, lw2, lb2, outc, out);
}